// Round 6
// baseline (406.645 us; speedup 1.0000x reference)
//
#include <hip/hip_runtime.h>

#define MESH  128
#define MESH2 16384
#define MESH3 2097152
#define NPART MESH3
#define TILE  16
#define CAP   6
typedef unsigned int u32;
typedef unsigned short u16;
typedef unsigned long long u64;

__device__ __forceinline__ float2 cmul(float2 a, float2 b) {
    return make_float2(a.x * b.x - a.y * b.y, a.x * b.y + a.y * b.x);
}
__device__ __forceinline__ float2 cmulc(float2 a, float2 b) {  // a * conj(b)
    return make_float2(a.x * b.x + a.y * b.y, a.y * b.x - a.x * b.y);
}
__device__ __forceinline__ u16 f2bf(float x) {
    u32 b = __float_as_uint(x);
    return (u16)((b + 0x7FFFu + ((b >> 16) & 1u)) >> 16);   // RNE
}

// ---------------- generic y-axis pass ----------------------------------------
template <bool INV>
__device__ __forceinline__ void fft_y_body(float2* __restrict__ data, int bid, int t) {
    __shared__ float2 s[MESH][TILE + 1];
    __shared__ float2 tw[64];
    if (t < 64) {
        float sv, cv;
        sincospif(-(float)t / 64.0f, &sv, &cv);
        tw[t] = make_float2(cv, INV ? -sv : sv);
    }
    const int outer = bid >> 3;
    const int z0 = (bid & 7) * TILE;
    const int base = outer * MESH2 + z0;
    for (int i = t; i < MESH * TILE; i += 256) {
        const int l = i & 15, e = i >> 4;
        s[e][l] = data[base + e * MESH + l];
    }
    __syncthreads();
    const int l  = t & 15;
    const int bb = t >> 4;
    if (!INV) {
        #pragma unroll
        for (int st = 0; st < 7; ++st) {
            const int logh = 6 - st;
            const int half = 1 << logh;
            #pragma unroll
            for (int it = 0; it < 4; ++it) {
                const int b  = bb + (it << 4);
                const int j  = b & (half - 1);
                const int g  = b >> logh;
                const int i0 = (g << (logh + 1)) + j;
                const int i1 = i0 + half;
                float2 u = s[i0][l], v = s[i1][l];
                float2 d = make_float2(u.x - v.x, u.y - v.y);
                s[i0][l] = make_float2(u.x + v.x, u.y + v.y);
                s[i1][l] = cmul(d, tw[j << st]);
            }
            __syncthreads();
        }
    } else {
        #pragma unroll
        for (int st = 0; st < 7; ++st) {
            const int half = 1 << st;
            #pragma unroll
            for (int it = 0; it < 4; ++it) {
                const int b  = bb + (it << 4);
                const int j  = b & (half - 1);
                const int g  = b >> st;
                const int i0 = (g << (st + 1)) + j;
                const int i1 = i0 + half;
                float2 u = s[i0][l];
                float2 v = cmul(s[i1][l], tw[j << (6 - st)]);
                s[i0][l] = make_float2(u.x + v.x, u.y + v.y);
                s[i1][l] = make_float2(u.x - v.x, u.y - v.y);
            }
            __syncthreads();
        }
    }
    for (int i = t; i < MESH * TILE; i += 256) {
        const int l2 = i & 15, e = i >> 4;
        data[base + e * MESH + l2] = s[e][l2];
    }
}

__global__ __launch_bounds__(256) void fft_y_fwd(float2* __restrict__ A) {
    fft_y_body<false>(A, blockIdx.x, threadIdx.x);
}
__global__ __launch_bounds__(256) void fft_y_inv_dual(float2* __restrict__ A,
                                                      float2* __restrict__ B) {
    float2* d = (blockIdx.x < 1024) ? A : B;
    fft_y_body<true>(d, blockIdx.x & 1023, threadIdx.x);
}

// ------- z-forward FFT fused with the staging-tile halo merge ----------------
__global__ __launch_bounds__(256) void fft_z_fwd_merge(const float* __restrict__ ST,
                                                       float2* __restrict__ out) {
    __shared__ float2 s[MESH][TILE + 1];
    __shared__ float2 tw[64];
    const int t = threadIdx.x;
    if (t < 64) {
        float sv, cv;
        sincospif(-(float)t / 64.0f, &sv, &cv);
        tw[t] = make_float2(cv, sv);
    }
    const int col0 = blockIdx.x * TILE;
    const int base = col0 * MESH;
    for (int i = t; i < MESH * TILE; i += 256) {
        const int lc = i >> 7;
        const int z  = i & 127;
        const int c  = col0 + lc;
        const int x = c >> 7, y = c & 127;
        const int tx = x >> 2, ty = y >> 1;
        const int hx = x & 3,  hy = y & 1;
        float v = ST[((tx << 6) | ty) * 1920 + ((hx * 3 + hy) << 7) + z];
        const int txm = (tx + 31) & 31;
        const int tym = (ty + 63) & 63;
        if (hx == 0)
            v += ST[((txm << 6) | ty) * 1920 + ((12 + hy) << 7) + z];
        if (hy == 0) {
            v += ST[((tx << 6) | tym) * 1920 + ((hx * 3 + 2) << 7) + z];
            if (hx == 0)
                v += ST[((txm << 6) | tym) * 1920 + (14 << 7) + z];
        }
        s[z][lc] = make_float2(v, 0.0f);
    }
    __syncthreads();
    const int l  = t & 15;
    const int bb = t >> 4;
    #pragma unroll
    for (int st = 0; st < 7; ++st) {
        const int logh = 6 - st;
        const int half = 1 << logh;
        #pragma unroll
        for (int it = 0; it < 4; ++it) {
            const int b  = bb + (it << 4);
            const int j  = b & (half - 1);
            const int g  = b >> logh;
            const int i0 = (g << (logh + 1)) + j;
            const int i1 = i0 + half;
            float2 u = s[i0][l], v = s[i1][l];
            float2 d = make_float2(u.x - v.x, u.y - v.y);
            s[i0][l] = make_float2(u.x + v.x, u.y + v.y);
            s[i1][l] = cmul(d, tw[j << st]);
        }
        __syncthreads();
    }
    for (int i = t; i < MESH * TILE; i += 256)
        out[base + i] = s[i & 127][i >> 7];
}

// ------- dual z-inverse FFT writing the packed bf16 force field F ------------
// F[g] (8B): bytes [0,4) = bf16 ax | bf16 ay<<16 ; bytes [4,6) = bf16 bz.
// blocks [0,1024) process A (writes u32 lo), [1024,2048) process B (writes u16).
__global__ __launch_bounds__(256) void fft_z_inv_pack(const float2* __restrict__ A,
                                                      const float2* __restrict__ B,
                                                      u32* __restrict__ Flo /* stride 2 */,
                                                      u16* __restrict__ Fhi /* stride 4 */) {
    __shared__ float2 s[MESH][TILE + 1];
    __shared__ float2 tw[64];
    const int t = threadIdx.x;
    if (t < 64) {
        float sv, cv;
        sincospif(-(float)t / 64.0f, &sv, &cv);
        tw[t] = make_float2(cv, -sv);
    }
    const bool isA = blockIdx.x < 1024;
    const int bid = blockIdx.x & 1023;
    const float2* in = isA ? A : B;
    const int base = bid * (TILE * MESH);
    for (int i = t; i < MESH * TILE; i += 256)
        s[i & 127][i >> 7] = in[base + i];
    __syncthreads();
    const int l  = t & 15;
    const int bb = t >> 4;
    #pragma unroll
    for (int st = 0; st < 7; ++st) {
        const int half = 1 << st;
        #pragma unroll
        for (int it = 0; it < 4; ++it) {
            const int b  = bb + (it << 4);
            const int j  = b & (half - 1);
            const int g  = b >> st;
            const int i0 = (g << (st + 1)) + j;
            const int i1 = i0 + half;
            float2 u = s[i0][l];
            float2 v = cmul(s[i1][l], tw[j << (6 - st)]);
            s[i0][l] = make_float2(u.x + v.x, u.y + v.y);
            s[i1][l] = make_float2(u.x - v.x, u.y - v.y);
        }
        __syncthreads();
    }
    if (isA) {
        for (int i = t; i < MESH * TILE; i += 256) {
            const float2 v = s[i & 127][i >> 7];
            Flo[2 * (base + i)] = (u32)f2bf(v.x) | ((u32)f2bf(v.y) << 16);
        }
    } else {
        for (int i = t; i < MESH * TILE; i += 256)
            Fhi[4 * (base + i) + 2] = f2bf(s[i & 127][i >> 7].x);
    }
}

// Fused: forward x-FFT (DIF) -> filter -> inverse x-FFT (DIT) on A and B lines.
__global__ __launch_bounds__(256) void fft_x_mega(float2* __restrict__ A,
                                                  float2* __restrict__ B) {
    __shared__ float2 SA[MESH][TILE + 1];
    __shared__ float2 SB[MESH][TILE + 1];
    __shared__ float2 tw[64];
    const int t = threadIdx.x;
    if (t < 64) {
        float sv, cv;
        sincospif(-(float)t / 64.0f, &sv, &cv);
        tw[t] = make_float2(cv, sv);
    }
    const int cy = blockIdx.x >> 3;
    const int z0 = (blockIdx.x & 7) * TILE;
    const int base = cy * MESH + z0;

    for (int i = t; i < MESH * TILE; i += 256) {
        const int l = i & 15, e = i >> 4;
        SA[e][l] = A[base + e * MESH2 + l];
    }
    __syncthreads();

    const int l  = t & 15;
    const int bb = t >> 4;
    #pragma unroll
    for (int st = 0; st < 7; ++st) {
        const int logh = 6 - st;
        const int half = 1 << logh;
        #pragma unroll
        for (int it = 0; it < 4; ++it) {
            const int b  = bb + (it << 4);
            const int j  = b & (half - 1);
            const int g  = b >> logh;
            const int i0 = (g << (logh + 1)) + j;
            const int i1 = i0 + half;
            float2 u = SA[i0][l], v = SA[i1][l];
            float2 d = make_float2(u.x - v.x, u.y - v.y);
            SA[i0][l] = make_float2(u.x + v.x, u.y + v.y);
            SA[i1][l] = cmul(d, tw[j << st]);
        }
        __syncthreads();
    }

    const int jy = (int)(__brev((unsigned)cy) >> 25);
    const float c = 6.28318530717958647692f / 128.0f;
    const float ky = c * (float)(jy < 64 ? jy : jy - 128);
    for (int i = t; i < MESH * TILE; i += 256) {
        const int e = i & 127, ll = i >> 7;
        const int jx = (int)(__brev((unsigned)e) >> 25);
        const int jz = (int)(__brev((unsigned)(z0 + ll)) >> 25);
        const float kx = c * (float)(jx < 64 ? jx : jx - 128);
        const float kz = c * (float)(jz < 64 ? jz : jz - 128);
        const float kk = kx * kx + ky * ky + kz * kz;
        float2 a = SA[e][ll];
        float2 av = make_float2(0.f, 0.f), bv = make_float2(0.f, 0.f);
        if (kk > 0.0f) {
            const float inv_kk = 1.0f / kk;
            const float rng = __expf(-0.09f * inv_kk - kk * kk);  // KL^2=0.09, KS^4=1
            const float sc  = -inv_kk * rng * (1.0f / 2097152.0f);
            const float pr = a.x * sc, pi = a.y * sc;
            av = make_float2(ky * pr + kx * pi, ky * pi - kx * pr);
            bv = make_float2(kz * pi, -kz * pr);
        }
        SA[e][ll] = av;
        SB[e][ll] = bv;
    }
    __syncthreads();

    #pragma unroll
    for (int st = 0; st < 7; ++st) {
        const int half = 1 << st;
        #pragma unroll
        for (int it = 0; it < 4; ++it) {
            const int b  = bb + (it << 4);
            const int j  = b & (half - 1);
            const int g  = b >> st;
            const int i0 = (g << (st + 1)) + j;
            const int i1 = i0 + half;
            const float2 w = tw[j << (6 - st)];
            float2 u = SA[i0][l];
            float2 v = cmulc(SA[i1][l], w);
            SA[i0][l] = make_float2(u.x + v.x, u.y + v.y);
            SA[i1][l] = make_float2(u.x - v.x, u.y - v.y);
            u = SB[i0][l];
            v = cmulc(SB[i1][l], w);
            SB[i0][l] = make_float2(u.x + v.x, u.y + v.y);
            SB[i1][l] = make_float2(u.x - v.x, u.y - v.y);
        }
        __syncthreads();
    }

    for (int i = t; i < MESH * TILE; i += 256) {
        const int l2 = i & 15, e = i >> 4;
        A[base + e * MESH2 + l2] = SA[e][l2];
        B[base + e * MESH2 + l2] = SB[e][l2];
    }
}

// ---------------- particle binning: 2048 buckets (4x2 columns) ----------------

__device__ __forceinline__ int bucket_of(float px, float py) {
    const int ix = ((int)floorf(px)) & 127;
    const int iy = ((int)floorf(py)) & 127;
    return ((ix >> 2) << 6) | (iy >> 1);
}

__global__ __launch_bounds__(256) void hist_kernel(const float* __restrict__ pos,
                                                   u32* __restrict__ cnt) {
    __shared__ u32 h[2048];
    const int t = threadIdx.x;
    for (int i = t; i < 2048; i += 256) h[i] = 0;
    __syncthreads();
    const int base_n = blockIdx.x * 8192;
    for (int it = 0; it < 32; ++it) {
        const int n = base_n + (it << 8) + t;
        atomicAdd(&h[bucket_of(pos[3 * n], pos[3 * n + 1])], 1u);
    }
    __syncthreads();
    for (int i = t; i < 2048; i += 256)
        if (h[i]) atomicAdd(&cnt[i], h[i]);
}

__global__ __launch_bounds__(1024) void scan_kernel(const u32* __restrict__ cnt,
                                                    u32* __restrict__ offsets,
                                                    u32* __restrict__ cursors) {
    __shared__ u32 tmp[1024];
    const int t = threadIdx.x;
    const u32 a = cnt[2 * t], b = cnt[2 * t + 1];
    const u32 s = a + b;
    tmp[t] = s;
    __syncthreads();
    for (int off = 1; off < 1024; off <<= 1) {
        const u32 v = (t >= off) ? tmp[t - off] : 0u;
        __syncthreads();
        tmp[t] += v;
        __syncthreads();
    }
    const u32 incl = tmp[t];
    const u32 excl = incl - s;
    offsets[2 * t + 1] = excl + a;
    offsets[2 * t + 2] = incl;
    cursors[2 * t]     = excl;
    cursors[2 * t + 1] = excl + a;
    if (t == 0) offsets[0] = 0;
}

// record (8B): [0,7) iz | [7,9) lx | [9,10) ly | [11,21) qx | [21,31) qy | [31,41) qz
__global__ __launch_bounds__(256) void scatter_kernel(const float* __restrict__ pos,
                                                      u32* __restrict__ cursors,
                                                      u64* __restrict__ S) {
    __shared__ u32 h[2048];
    const int t = threadIdx.x;
    for (int i = t; i < 2048; i += 256) h[i] = 0;
    __syncthreads();
    const int base_n = blockIdx.x * 8192;
    for (int it = 0; it < 32; ++it) {
        const int n = base_n + (it << 8) + t;
        atomicAdd(&h[bucket_of(pos[3 * n], pos[3 * n + 1])], 1u);
    }
    __syncthreads();
    for (int i = t; i < 2048; i += 256) {
        const u32 c = h[i];
        h[i] = c ? atomicAdd(&cursors[i], c) : 0u;
    }
    __syncthreads();
    for (int it = 0; it < 32; ++it) {
        const int n = base_n + (it << 8) + t;
        const float px = pos[3 * n], py = pos[3 * n + 1], pz = pos[3 * n + 2];
        const float fxx = floorf(px), fyy = floorf(py), fzz = floorf(pz);
        const int ix = ((int)fxx) & 127, iy = ((int)fyy) & 127, iz = ((int)fzz) & 127;
        const int b = ((ix >> 2) << 6) | (iy >> 1);
        const u32 qx = (u32)((px - fxx) * 1024.0f);
        const u32 qy = (u32)((py - fyy) * 1024.0f);
        const u32 qz = (u32)((pz - fzz) * 1024.0f);
        const u64 v = (u64)iz | ((u64)(ix & 3) << 7) | ((u64)(iy & 1) << 9)
                    | ((u64)qx << 11) | ((u64)qy << 21) | ((u64)qz << 31);
        S[atomicAdd(&h[b], 1u)] = v;
    }
}

// GATHER-based paint (unchanged from round 5).
__global__ __launch_bounds__(256) void paint_kernel(const u64* __restrict__ S,
                                                    const u32* __restrict__ offsets,
                                                    float* __restrict__ ST) {
    __shared__ u32 cnt[1024];
    __shared__ u32 rec[1024 * CAP];
    __shared__ u64 ovf[128];
    __shared__ u32 novf;
    const int t = threadIdx.x;
    for (int i = t; i < 1024; i += 256) cnt[i] = 0;
    if (t == 0) novf = 0;
    __syncthreads();
    const int b = blockIdx.x;
    const int start = offsets[b], end = offsets[b + 1];
    for (int i = start + t; i < end; i += 256) {
        const u64 v = S[i];
        const int iz = (int)(v & 127);
        const int lx = (int)((v >> 7) & 3);
        const int ly = (int)((v >> 9) & 1);
        const int cell = (((lx << 1) | ly) << 7) | iz;
        const u32 r = (u32)((v >> 11) & 0x3FFFFFFFull);
        const u32 slot = atomicAdd(&cnt[cell], 1u);
        if (slot < CAP) rec[cell * CAP + slot] = r;
        else {
            const u32 o = atomicAdd(&novf, 1u);
            if (o < 128u) ovf[o] = ((u64)cell << 32) | r;
        }
    }
    __syncthreads();
    const u32 nv = novf > 128u ? 128u : novf;
    const float inv = 1.0f / 1024.0f;
    for (int i = t; i < 1920; i += 256) {
        const int hx = i / 384;
        const int hy = (i >> 7) % 3;
        const int z  = i & 127;
        float acc = 0.0f;
        #pragma unroll
        for (int sx = 0; sx < 2; ++sx) {
            const int bx = hx - 1 + sx;
            if ((unsigned)bx > 3u) continue;
            #pragma unroll
            for (int sy = 0; sy < 2; ++sy) {
                const int by = hy - 1 + sy;
                if ((unsigned)by > 1u) continue;
                #pragma unroll
                for (int sz = 0; sz < 2; ++sz) {
                    const int bz = (z - 1 + sz) & 127;
                    const int c = (((bx << 1) | by) << 7) | bz;
                    const int m = (int)min(cnt[c], (u32)CAP);
                    const int rb = c * CAP;
                    for (int k = 0; k < m; ++k) {
                        const u32 r = rec[rb + k];
                        const float fx = (float)(r & 1023) * inv;
                        const float fy = (float)((r >> 10) & 1023) * inv;
                        const float fz = (float)(r >> 20) * inv;
                        const float wx = sx ? (1.0f - fx) : fx;
                        const float wy = sy ? (1.0f - fy) : fy;
                        const float wz = sz ? (1.0f - fz) : fz;
                        acc += wx * wy * wz;
                    }
                }
            }
        }
        for (u32 j = 0; j < nv; ++j) {
            const u64 o = ovf[j];
            const int c = (int)(o >> 32);
            const int obx = (c >> 8) & 3, oby = (c >> 7) & 1, obz = c & 127;
            const int dx = hx - obx, dy = hy - oby, dz = (z - obz) & 127;
            if ((unsigned)dx < 2u && (unsigned)dy < 2u && dz < 2) {
                const u32 r = (u32)o;
                const float fx = (float)(r & 1023) * inv;
                const float fy = (float)((r >> 10) & 1023) * inv;
                const float fz = (float)(r >> 20) * inv;
                acc += (dx ? fx : 1.0f - fx) * (dy ? fy : 1.0f - fy)
                     * (dz ? fz : 1.0f - fz);
            }
        }
        ST[(size_t)b * 1920 + i] = acc;
    }
}

// Unsorted readout: coalesced pos/vel/out streams, random F gathers (LLC).
__global__ __launch_bounds__(256) void readout_kernel(const float* __restrict__ pos,
                                                      const float* __restrict__ vel,
                                                      const float* __restrict__ fdf,
                                                      const u64* __restrict__ F,
                                                      float* __restrict__ out) {
    const int n = blockIdx.x * 256 + threadIdx.x;
    if (n >= NPART) return;
    const float px = pos[3 * n], py = pos[3 * n + 1], pz = pos[3 * n + 2];
    const float fxx = floorf(px), fyy = floorf(py), fzz = floorf(pz);
    const int ix0 = (int)fxx, iy0 = (int)fyy, iz0 = (int)fzz;
    const float fx = px - fxx, fy = py - fyy, fz = pz - fzz;
    const int xs[2] = {(ix0 & 127) << 14, ((ix0 + 1) & 127) << 14};
    const int ys[2] = {(iy0 & 127) << 7, ((iy0 + 1) & 127) << 7};
    const int zs[2] = {iz0 & 127, (iz0 + 1) & 127};
    const float wx[2] = {1.0f - fx, fx};
    const float wy[2] = {1.0f - fy, fy};
    const float wz[2] = {1.0f - fz, fz};
    float gx = 0.f, gy = 0.f, gz = 0.f;
    #pragma unroll
    for (int dx = 0; dx < 2; ++dx)
        #pragma unroll
        for (int dy = 0; dy < 2; ++dy) {
            const int gb = xs[dx] | ys[dy];
            const float wxy = wx[dx] * wy[dy];
            #pragma unroll
            for (int dz = 0; dz < 2; ++dz) {
                const u64 f = F[gb | zs[dz]];
                const float w = wxy * wz[dz];
                gx += w * __uint_as_float((u32)f << 16);
                gy += w * __uint_as_float((u32)f & 0xFFFF0000u);
                gz += w * __uint_as_float((u32)((f >> 32) & 0xFFFFull) << 16);
            }
        }
    const float sc = 0.2f / fdf[0];
    out[3 * NPART + 3 * n + 0] = vel[3 * n + 0] + gx * sc;
    out[3 * NPART + 3 * n + 1] = vel[3 * n + 1] + gy * sc;
    out[3 * NPART + 3 * n + 2] = vel[3 * n + 2] + gz * sc;
}

extern "C" void kernel_launch(void* const* d_in, const int* in_sizes, int n_in,
                              void* d_out, int out_size, void* d_ws, size_t ws_size,
                              hipStream_t stream) {
    const float* pos = (const float*)d_in[0];
    const float* vel = (const float*)d_in[1];
    const float* fdf = (const float*)d_in[2];
    float* out = (float*)d_out;

    float2* A  = (float2*)d_ws;            // 16.78 MB complex grid
    float2* B  = A + MESH3;                // 16.78 MB complex grid
    float*  ST = (float*)B;                // 15.7 MB paint staging (dead before mega writes B)
    // d_out pos-half scratch (dead before the final pos memcpy):
    u64* S = (u64*)d_out;                  // 16.78 MB sorted particles (dead after paint)
    u64* F = (u64*)d_out;                  // 16.78 MB packed force field (written after paint)
    u32* cnt     = (u32*)((char*)d_out + (21 << 20));   // 2048 (dead after scan)
    u32* offsets = cnt + 2048;                          // 2049 (dead after paint)
    u32* cursors = offsets + 2049;                      // 2048

    hipMemsetAsync(cnt, 0, 2048 * sizeof(u32), stream);
    hist_kernel<<<256, 256, 0, stream>>>(pos, cnt);
    scan_kernel<<<1, 1024, 0, stream>>>(cnt, offsets, cursors);
    scatter_kernel<<<256, 256, 0, stream>>>(pos, cursors, S);

    paint_kernel<<<2048, 256, 0, stream>>>(S, offsets, ST);

    fft_z_fwd_merge<<<1024, 256, 0, stream>>>(ST, A);   // halo merge + fwd z
    fft_y_fwd<<<1024, 256, 0, stream>>>(A);
    fft_x_mega<<<1024, 256, 0, stream>>>(A, B);         // fwd x + filter + inv x (A,B)
    fft_y_inv_dual<<<2048, 256, 0, stream>>>(A, B);     // inv y on both grids
    fft_z_inv_pack<<<2048, 256, 0, stream>>>(A, B, (u32*)F, (u16*)F);  // -> packed F

    readout_kernel<<<NPART / 256, 256, 0, stream>>>(pos, vel, fdf, F, out);
    hipMemcpyAsync(out, pos, (size_t)NPART * 3 * sizeof(float),
                   hipMemcpyDeviceToDevice, stream);
}